// Round 8
// baseline (5144.525 us; speedup 1.0000x reference)
//
#include <hip/hip_runtime.h>
#include <stdint.h>

// Experts FFN: E experts, C tokens/expert, D model, F ff
#define E_ 8
#define C_ 4096
#define D_ 1024
#define F_ 4096

typedef __attribute__((ext_vector_type(8))) short bf16x8;
typedef __attribute__((ext_vector_type(4))) float f32x4;
typedef __attribute__((ext_vector_type(8))) unsigned short u16x8;
typedef __attribute__((ext_vector_type(4))) unsigned short u16x4;

__device__ __forceinline__ unsigned short f2bf(float x) {
  union { float f; uint32_t u; } v; v.f = x;
  uint32_t r = v.u + 0x7FFFu + ((v.u >> 16) & 1u);  // RNE
  return (unsigned short)(r >> 16);
}

// JAX gelu (approximate=True)
__device__ __forceinline__ float gelu_f(float x) {
  float x3 = x * x * x;
  float u = 0.7978845608028654f * __builtin_fmaf(0.044715f, x3, x);
  float t = __expf(2.0f * u);
  float th = 1.0f - 2.0f / (t + 1.0f);
  return 0.5f * x * (1.0f + th);
}

// ============================================================================
// Packed operand format (per 256-row panel, per 64-k tile; 32KB blocks):
//   elem offset = h*8192 + c*1024 + r7*8 + e
//   (h = row>>7 in panel, c = (k&63)>>3, r7 = row&127, e = k&7)   [R6-verified]
// ============================================================================

// ---- pack_rm: fp32 [R][K] row-major -> packed bf16 ----
__global__ __launch_bounds__(256) void pack_rm_kernel(
    const float* __restrict__ in, unsigned short* __restrict__ out,
    int R, int K) {
  const int p = blockIdx.x, t = blockIdx.y, ge = blockIdx.z;
  const float* src = in + (size_t)ge * R * K + (size_t)(p * 256) * K + t * 64;
  unsigned short* dst =
      out + ((size_t)(ge * (R >> 8) + p) * (K >> 6) + t) * 16384;
  __shared__ unsigned short sm[256 * 72];
  const int tid = threadIdx.x;
  const int rb = tid >> 4, k4 = (tid & 15) * 4;
#pragma unroll
  for (int i = 0; i < 16; ++i) {
    int r = rb + i * 16;
    float4 v = *(const float4*)(src + (size_t)r * K + k4);
    u16x4 o;
    o[0] = f2bf(v.x); o[1] = f2bf(v.y); o[2] = f2bf(v.z); o[3] = f2bf(v.w);
    *(u16x4*)&sm[r * 72 + k4] = o;
  }
  __syncthreads();
#pragma unroll
  for (int w = 0; w < 8; ++w) {
    int o = tid * 8 + w * 2048;
    int h = o >> 13, c = (o >> 10) & 7, r7 = (o >> 3) & 127;
    int row = h * 128 + r7;
    u16x8 v = *(const u16x8*)&sm[row * 72 + c * 8];
    *(u16x8*)(dst + o) = v;
  }
}

// ---- pack_tr: fp32 [K][N] -> packed bf16 of transpose [N][K] ----
__global__ __launch_bounds__(256) void pack_tr_kernel(
    const float* __restrict__ in, unsigned short* __restrict__ out,
    int K, int N) {
  const int pn = blockIdx.x, tk = blockIdx.y, ge = blockIdx.z;
  const float* src = in + (size_t)ge * K * N + (size_t)(tk * 64) * N + pn * 256;
  unsigned short* dst =
      out + ((size_t)(ge * (N >> 8) + pn) * (K >> 6) + tk) * 16384;
  __shared__ unsigned short sm[64 * 260];
  const int tid = threadIdx.x;
  const int kb = tid >> 6, n4 = (tid & 63) * 4;
#pragma unroll
  for (int i = 0; i < 16; ++i) {
    int kk = kb + i * 4;
    float4 v = *(const float4*)(src + (size_t)kk * N + n4);
    u16x4 o;
    o[0] = f2bf(v.x); o[1] = f2bf(v.y); o[2] = f2bf(v.z); o[3] = f2bf(v.w);
    *(u16x4*)&sm[kk * 260 + n4] = o;
  }
  __syncthreads();
#pragma unroll
  for (int w = 0; w < 8; ++w) {
    int o = tid * 8 + w * 2048;
    int h = o >> 13, c = (o >> 10) & 7, r7 = (o >> 3) & 127;
    int n = h * 128 + r7;
    u16x8 v;
#pragma unroll
    for (int e = 0; e < 8; ++e) v[e] = sm[(c * 8 + e) * 260 + n];
    *(u16x8*)(dst + o) = v;
  }
}

// ---- async global->LDS ----
typedef const __attribute__((address_space(1))) uint32_t* gas1_ptr;
typedef __attribute__((address_space(3))) uint32_t* las3_ptr;

__device__ __forceinline__ void async16(const void* g, void* l) {
  __builtin_amdgcn_global_load_lds((gas1_ptr)(uintptr_t)g, (las3_ptr)(uintptr_t)l,
                                   16, 0, 0);
}

// ============================================================================
// 256x256 bf16 GEMM, 2-blocks/CU inter-block-overlap structure:
//  - A: packed, global_load_lds double-buffered (64 KiB LDS total -> 2 blk/CU)
//  - B: packed, DIRECT global->register (bypasses LDS; frag = 4x256B
//    contiguous per wave). Removes 1/3 of LDS reads + 1/2 of DMA writes.
//  - one __syncthreads() per K-tile (auto vmcnt/lgkm drain); NO fences; the
//    drain stall of one block is covered by the co-resident block (m97/m114).
//  - frag regs alternate (aE/aO, B0/B1) -> no WAR vs in-flight MFMA.
// MODE 0: fp32 out row-major via LDS repack. MODE 1: bf16 gelu out PACKED.
// ============================================================================

template <int MODE>
__global__ __launch_bounds__(512, 4) void gemm256_kernel(
    const unsigned short* __restrict__ A,  // packed [panels][NT][32KB]
    const unsigned short* __restrict__ B,  // packed [panels][NT][32KB]
    const float* __restrict__ bias,        // [N]
    void* __restrict__ Cout,
    int K, int N, int numM, int numN,
    size_t aStride, size_t bStride, size_t cStride, int biasStride) {
  __shared__ char lds[65536];
  char* ldsp = (char*)lds;

  const int NT = K >> 6;

  // bijective XCD swizzle (m204)
  int lin = blockIdx.x;
  int nwg = gridDim.x;
  int qq = nwg >> 3, rr8 = nwg & 7;
  int xcd = lin & 7, idx = lin >> 3;
  int wg = (xcd < rr8 ? xcd * (qq + 1) : rr8 * (qq + 1) + (xcd - rr8) * qq) + idx;
  int per = numM * numN;
  int e = wg / per;
  int rem = wg - e * per;
  int tm = rem % numM, tn = rem / numM;

  const int rowTile = tm << 8;
  const int colTile = tn << 8;

  const int tid = threadIdx.x;
  const int lane = tid & 63;
  const int w = tid >> 6;
  const int wm = w & 1, wn = w >> 1;
  const int l15 = lane & 15, q = lane >> 4;

  // ---- A staging: linear contiguous 32KB packed tiles ----
  const char* Ag = (const char*)(A + (size_t)e * aStride) +
                   (size_t)tm * NT * 32768 + tid * 16;
  char* ldT = ldsp + tid * 16;

#define STAGE_A(bb, kt) do { \
    const char* as_ = Ag + (size_t)(kt) * 32768; \
    char* ld_ = ldT + (bb) * 32768; \
    async16(as_, ld_);                 async16(as_ + 8192, ld_ + 8192); \
    async16(as_ + 16384, ld_ + 16384); async16(as_ + 24576, ld_ + 24576); \
  } while (0)

  // ---- A frag reads (packed: wm-half, c=ks*4+q, r7=mf*16+l15) ----
  const int aRd = wm * 16384 + q * 2048 + l15 * 16;

#define READ_AF(dst, bb) do { \
    _Pragma("unroll") for (int mf = 0; mf < 8; ++mf) \
    _Pragma("unroll") for (int ks = 0; ks < 2; ++ks) \
      dst[mf][ks] = *(const bf16x8*)(ldsp + (bb) * 32768 + aRd + \
                                     ks * 8192 + mf * 256); \
  } while (0)

  // ---- B direct-to-reg (packed: h=wn>>1, c=ks*4+q, r7=(wn&1)*64+nf*16+l15) ----
  const char* Bg = (const char*)(B + (size_t)e * bStride) +
                   (size_t)tn * NT * 32768 + (wn >> 1) * 16384 + q * 2048 +
                   ((wn & 1) * 64 + l15) * 16;

#define B_LOAD(dst, kt) do { \
    const char* bt_ = Bg + (size_t)(kt) * 32768; \
    _Pragma("unroll") for (int nf = 0; nf < 4; ++nf) \
    _Pragma("unroll") for (int ks = 0; ks < 2; ++ks) \
      dst[nf][ks] = *(const bf16x8*)(bt_ + ks * 8192 + nf * 256); \
  } while (0)

  bf16x8 aE[8][2], aO[8][2], B0[4][2], B1[4][2];
  f32x4 acc[8][4];
#pragma unroll
  for (int m = 0; m < 8; ++m)
#pragma unroll
    for (int n = 0; n < 4; ++n) acc[m][n] = {0.f, 0.f, 0.f, 0.f};

#define MFMA64(AF, BF) do { \
    _Pragma("unroll") for (int mf = 0; mf < 8; ++mf) \
    _Pragma("unroll") for (int nf = 0; nf < 4; ++nf) \
    _Pragma("unroll") for (int ks = 0; ks < 2; ++ks) \
      acc[mf][nf] = __builtin_amdgcn_mfma_f32_16x16x32_bf16( \
          BF[nf][ks], AF[mf][ks], acc[mf][nf], 0, 0, 0); \
  } while (0)

  // per K-tile: sync(drain) -> prefetch next (A->LDS, B->regs) -> reads -> MFMA
#define ITER(cb, nb, AF, CURB, NXTB, tn_) do { \
    __syncthreads(); \
    STAGE_A(nb, tn_); \
    B_LOAD(NXTB, tn_); \
    READ_AF(AF, cb); \
    MFMA64(AF, CURB); \
  } while (0)

  // ---- prologue ----
  STAGE_A(0, 0);
  B_LOAD(B0, 0);

  const int NP = NT >> 1;
  for (int j = 0; j < NP; ++j) {
    int t1 = 2 * j + 1;
    int t2 = 2 * j + 2; if (t2 > NT - 1) t2 = NT - 1;  // dummy last prefetch
    ITER(0, 1, aE, B0, B1, t1);
    ITER(1, 0, aO, B1, B0, t2);
  }
  __syncthreads();  // drain dummy prefetch; LDS free for epilogue reuse

  if constexpr (MODE == 1) {
    // ---- epilogue -> PACKED H (bf16, gelu): coalesced 256B blocks ----
    unsigned short* Hb = (unsigned short*)Cout + (size_t)e * cStride;
    unsigned short* Hw = Hb +
        ((size_t)(tm * (N >> 6) + tn * 4 + wn) * 2 + wm) * 8192 +
        (q >> 1) * 1024 + l15 * 8 + (q & 1) * 4;
#pragma unroll
    for (int nf = 0; nf < 4; ++nf) {
      int col = colTile + wn * 64 + nf * 16 + q * 4;
      float4 bv = *(const float4*)(bias + e * biasStride + col);
#pragma unroll
      for (int mf = 0; mf < 8; ++mf) {
        f32x4 v = acc[mf][nf];
        u16x4 o;
        o[0] = f2bf(gelu_f(v[0] + bv.x));
        o[1] = f2bf(gelu_f(v[1] + bv.y));
        o[2] = f2bf(gelu_f(v[2] + bv.z));
        o[3] = f2bf(gelu_f(v[3] + bv.w));
        *(u16x4*)(Hw + nf * 2048 + mf * 128) = o;
      }
    }
  } else {
    // ---- epilogue -> row-major fp32 Y via LDS repack (coalesced) ----
    float* smf = (float*)ldsp;  // [32][260] fp32 = 33 KB
    float* Yb = (float*)Cout + (size_t)e * cStride;
    const int srow = wm * 16 + l15;
    float4 bv[4];
#pragma unroll
    for (int nf = 0; nf < 4; ++nf)
      bv[nf] = *(const float4*)(bias + e * biasStride + colTile + wn * 64 +
                                nf * 16 + q * 4);
#pragma unroll
    for (int mf = 0; mf < 8; ++mf) {
#pragma unroll
      for (int nf = 0; nf < 4; ++nf) {
        f32x4 v = acc[mf][nf];
        f32x4 o = {v[0] + bv[nf].x, v[1] + bv[nf].y,
                   v[2] + bv[nf].z, v[3] + bv[nf].w};
        *(f32x4*)&smf[srow * 260 + wn * 64 + nf * 16 + q * 4] = o;
      }
      __syncthreads();
      {
        int r32 = tid >> 4, seg = tid & 15;
        int row = rowTile + (r32 >> 4) * 128 + mf * 16 + (r32 & 15);
        float* yr = Yb + (size_t)row * N + colTile + seg * 16;
        float4 v0 = *(float4*)&smf[r32 * 260 + seg * 16 + 0];
        float4 v1 = *(float4*)&smf[r32 * 260 + seg * 16 + 4];
        float4 v2 = *(float4*)&smf[r32 * 260 + seg * 16 + 8];
        float4 v3 = *(float4*)&smf[r32 * 260 + seg * 16 + 12];
        *(float4*)(yr + 0) = v0;
        *(float4*)(yr + 4) = v1;
        *(float4*)(yr + 8) = v2;
        *(float4*)(yr + 12) = v3;
      }
      __syncthreads();
    }
  }
}

extern "C" void kernel_launch(void* const* d_in, const int* in_sizes, int n_in,
                              void* d_out, int out_size, void* d_ws, size_t ws_size,
                              hipStream_t stream) {
  const float* X = (const float*)d_in[0];   // [1][E*C][D]
  const float* W1 = (const float*)d_in[1];  // [E][D][F]
  const float* b1 = (const float*)d_in[2];  // [E][F]
  const float* W2 = (const float*)d_in[3];  // [E][F][D]
  const float* b2 = (const float*)d_in[4];  // [E][D]
  float* Y = (float*)d_out;                 // [1][E*C][D]

  const size_t szX = (size_t)C_ * D_ * 2;
  const size_t szW1 = (size_t)F_ * D_ * 2;
  const size_t szW2 = (size_t)D_ * F_ * 2;
  const size_t szH = (size_t)C_ * F_ * 2;
  const size_t fixed = szX + szW1 + szW2;

  int g = 0;
  {
    const int cands[4] = {8, 4, 2, 1};
    for (int i = 0; i < 4; ++i)
      if ((fixed + szH) * (size_t)cands[i] <= ws_size) { g = cands[i]; break; }
  }
  int RC = C_;
  if (g == 0) {  // tiny-ws fallback: chunk rows (256-granular)
    g = 1;
    size_t avail = ws_size > fixed ? ws_size - fixed : 0;
    RC = (int)(avail / ((size_t)F_ * 2));
    RC = (RC / 256) * 256;
    if (RC < 256) RC = 256;
    if (RC > C_) RC = C_;
  }

  unsigned short* XP = (unsigned short*)d_ws;              // [g] packed X
  unsigned short* W1P = XP + (size_t)g * C_ * D_;          // [g] packed W1^T
  unsigned short* W2P = W1P + (size_t)g * F_ * D_;         // [g] packed W2^T
  unsigned short* HP = W2P + (size_t)g * D_ * F_;          // [g] packed H

  const int numN1 = F_ / 256;  // 16
  const int numN2 = D_ / 256;  // 4
  const int NT1 = D_ / 64;     // 16

  for (int e0 = 0; e0 < E_; e0 += g) {
    pack_rm_kernel<<<dim3(C_ / 256, D_ / 64, g), 256, 0, stream>>>(
        X + (size_t)e0 * C_ * D_, XP, C_, D_);
    pack_tr_kernel<<<dim3(F_ / 256, D_ / 64, g), 256, 0, stream>>>(
        W1 + (size_t)e0 * D_ * F_, W1P, D_, F_);
    pack_tr_kernel<<<dim3(D_ / 256, F_ / 64, g), 256, 0, stream>>>(
        W2 + (size_t)e0 * F_ * D_, W2P, F_, D_);

    for (int r0 = 0; r0 < C_; r0 += RC) {
      int numM = RC / 256;
      // GEMM1: H = gelu(X @ W1 + b1) -> packed H, [RC x F], K = D
      gemm256_kernel<1><<<dim3((unsigned)(numM * numN1 * g)), 512, 0, stream>>>(
          XP + (size_t)(r0 >> 8) * NT1 * 16384, W1P, b1 + (size_t)e0 * F_,
          (void*)HP, D_, F_, numM, numN1,
          (size_t)C_ * D_, (size_t)F_ * D_, (size_t)RC * F_, F_);
      // GEMM2: Y = H @ W2 + b2, [RC x D], K = F
      gemm256_kernel<0><<<dim3((unsigned)(numM * numN2 * g)), 512, 0, stream>>>(
          HP, W2P, b2 + (size_t)e0 * D_,
          (void*)(Y + (size_t)e0 * C_ * D_ + (size_t)r0 * D_),
          F_, D_, numM, numN2,
          (size_t)RC * F_, (size_t)D_ * F_, (size_t)C_ * D_, D_);
    }
  }
}

// Round 9
// 1071.154 us; speedup vs baseline: 4.8028x; 4.8028x over previous
//
#include <hip/hip_runtime.h>
#include <stdint.h>

// Experts FFN: E experts, C tokens/expert, D model, F ff
#define E_ 8
#define C_ 4096
#define D_ 1024
#define F_ 4096

typedef __attribute__((ext_vector_type(8))) short bf16x8;
typedef __attribute__((ext_vector_type(4))) float f32x4;
typedef __attribute__((ext_vector_type(8))) unsigned short u16x8;
typedef __attribute__((ext_vector_type(4))) unsigned short u16x4;

__device__ __forceinline__ unsigned short f2bf(float x) {
  union { float f; uint32_t u; } v; v.f = x;
  uint32_t r = v.u + 0x7FFFu + ((v.u >> 16) & 1u);  // RNE
  return (unsigned short)(r >> 16);
}

// JAX gelu (approximate=True)
__device__ __forceinline__ float gelu_f(float x) {
  float x3 = x * x * x;
  float u = 0.7978845608028654f * __builtin_fmaf(0.044715f, x3, x);
  float t = __expf(2.0f * u);
  float th = 1.0f - 2.0f / (t + 1.0f);
  return 0.5f * x * (1.0f + th);
}

// ============================================================================
// Packed operand format (per 256-row panel, per 64-k tile; 16384-elem blocks):
//   elem offset = h*8192 + c*1024 + r7*8 + e
//   (h = row>>7 in panel, c = (k&63)>>3, r7 = row&127, e = k&7)   [R6-verified]
// A 128-row tile = one h-half = 16KB contiguous -> 4 linear async16 per thread.
// ============================================================================

// ---- pack_rm: fp32 [R][K] row-major -> packed bf16 ----
__global__ __launch_bounds__(256) void pack_rm_kernel(
    const float* __restrict__ in, unsigned short* __restrict__ out,
    int R, int K) {
  const int p = blockIdx.x, t = blockIdx.y, ge = blockIdx.z;
  const float* src = in + (size_t)ge * R * K + (size_t)(p * 256) * K + t * 64;
  unsigned short* dst =
      out + ((size_t)(ge * (R >> 8) + p) * (K >> 6) + t) * 16384;
  __shared__ unsigned short sm[256 * 72];
  const int tid = threadIdx.x;
  const int rb = tid >> 4, k4 = (tid & 15) * 4;
#pragma unroll
  for (int i = 0; i < 16; ++i) {
    int r = rb + i * 16;
    float4 v = *(const float4*)(src + (size_t)r * K + k4);
    u16x4 o;
    o[0] = f2bf(v.x); o[1] = f2bf(v.y); o[2] = f2bf(v.z); o[3] = f2bf(v.w);
    *(u16x4*)&sm[r * 72 + k4] = o;
  }
  __syncthreads();
#pragma unroll
  for (int w = 0; w < 8; ++w) {
    int o = tid * 8 + w * 2048;
    int h = o >> 13, c = (o >> 10) & 7, r7 = (o >> 3) & 127;
    int row = h * 128 + r7;
    u16x8 v = *(const u16x8*)&sm[row * 72 + c * 8];
    *(u16x8*)(dst + o) = v;
  }
}

// ---- pack_tr: fp32 [K][N] -> packed bf16 of transpose [N][K] ----
__global__ __launch_bounds__(256) void pack_tr_kernel(
    const float* __restrict__ in, unsigned short* __restrict__ out,
    int K, int N) {
  const int pn = blockIdx.x, tk = blockIdx.y, ge = blockIdx.z;
  const float* src = in + (size_t)ge * K * N + (size_t)(tk * 64) * N + pn * 256;
  unsigned short* dst =
      out + ((size_t)(ge * (N >> 8) + pn) * (K >> 6) + tk) * 16384;
  __shared__ unsigned short sm[64 * 260];
  const int tid = threadIdx.x;
  const int kb = tid >> 6, n4 = (tid & 63) * 4;
#pragma unroll
  for (int i = 0; i < 16; ++i) {
    int kk = kb + i * 4;
    float4 v = *(const float4*)(src + (size_t)kk * N + n4);
    u16x4 o;
    o[0] = f2bf(v.x); o[1] = f2bf(v.y); o[2] = f2bf(v.z); o[3] = f2bf(v.w);
    *(u16x4*)&sm[kk * 260 + n4] = o;
  }
  __syncthreads();
#pragma unroll
  for (int w = 0; w < 8; ++w) {
    int o = tid * 8 + w * 2048;
    int h = o >> 13, c = (o >> 10) & 7, r7 = (o >> 3) & 127;
    int n = h * 128 + r7;
    u16x8 v;
#pragma unroll
    for (int e = 0; e < 8; ++e) v[e] = sm[(c * 8 + e) * 260 + n];
    *(u16x8*)(dst + o) = v;
  }
}

// ---- async global->LDS ----
typedef const __attribute__((address_space(1))) uint32_t* gas1_ptr;
typedef __attribute__((address_space(3))) uint32_t* las3_ptr;

__device__ __forceinline__ void async16(const void* g, void* l) {
  __builtin_amdgcn_global_load_lds((gas1_ptr)(uintptr_t)g, (las3_ptr)(uintptr_t)l,
                                   16, 0, 0);
}

// ============================================================================
// 128x128 bf16 GEMM, m97-replica on packed operands (3 blocks/CU):
//  - 256 thr = 4 waves (2M x 2N), per-wave 64x64 -> acc 64 VGPR, ~160 total.
//  - single-buffered 32 KiB LDS; plain __syncthreads() x2 per K-tile; the
//    drain stalls are hidden by 3 co-resident blocks (m97/m114 mechanism).
//  - staging: 8 fully-linear async16/thread (packed tiles, perfect coalesce).
//  - LDS frag reads 16B-consecutive per 16 lanes -> conflict-free, no swizzle.
//  - no fences / setprio / manual waitcnt; no launch_bounds occupancy forcing.
// MODE 0: fp32 out row-major via LDS repack. MODE 1: bf16 gelu out PACKED.
// ============================================================================

template <int MODE>
__global__ __launch_bounds__(256) void gemm128_kernel(
    const unsigned short* __restrict__ A,  // packed [panelsM][NT][16384e]
    const unsigned short* __restrict__ B,  // packed [panelsN][NT][16384e]
    const float* __restrict__ bias,        // [N]
    void* __restrict__ Cout,
    int K, int N, int numM, int numN,      // tile counts in 128 units
    size_t aStride, size_t bStride, size_t cStride, int biasStride) {
  __shared__ char lds[32768];
  char* ldsp = (char*)lds;

  const int NT = K >> 6;

  // bijective XCD swizzle (m204)
  int lin = blockIdx.x;
  int nwg = gridDim.x;
  int qq = nwg >> 3, rr8 = nwg & 7;
  int xcd = lin & 7, idx = lin >> 3;
  int wg = (xcd < rr8 ? xcd * (qq + 1) : rr8 * (qq + 1) + (xcd - rr8) * qq) + idx;
  int per = numM * numN;
  int e = wg / per;
  int rem = wg - e * per;
  int tm = rem % numM, tn = rem / numM;

  const int tid = threadIdx.x;
  const int lane = tid & 63;
  const int w = tid >> 6;
  const int wm = w & 1, wn = w >> 1;      // 2x2 wave grid
  const int l15 = lane & 15, q = lane >> 4;

  // ---- staging bases: 128-tile = h-half of a 256-panel packed block ----
  const char* Ag = (const char*)(A + (size_t)e * aStride) +
                   (size_t)(tm >> 1) * NT * 32768 + (tm & 1) * 16384 + tid * 16;
  const char* Bg = (const char*)(B + (size_t)e * bStride) +
                   (size_t)(tn >> 1) * NT * 32768 + (tn & 1) * 16384 + tid * 16;
  char* ldA = ldsp + tid * 16;
  char* ldB = ldsp + 16384 + tid * 16;

#define STAGE(kt) do { \
    const char* a_ = Ag + (size_t)(kt) * 32768; \
    const char* b_ = Bg + (size_t)(kt) * 32768; \
    async16(a_, ldA);          async16(a_ + 4096, ldA + 4096); \
    async16(a_ + 8192, ldA + 8192);  async16(a_ + 12288, ldA + 12288); \
    async16(b_, ldB);          async16(b_ + 4096, ldB + 4096); \
    async16(b_ + 8192, ldB + 8192);  async16(b_ + 12288, ldB + 12288); \
  } while (0)

  // ---- frag read bases (packed in-LDS: c*2048B + r*16B) ----
  const int aRd = q * 2048 + (wm * 64 + l15) * 16;
  const int bRd = 16384 + q * 2048 + (wn * 64 + l15) * 16;

  bf16x8 aF[4][2], bF[4][2];
  f32x4 acc[4][4];
#pragma unroll
  for (int m = 0; m < 4; ++m)
#pragma unroll
    for (int n = 0; n < 4; ++n) acc[m][n] = {0.f, 0.f, 0.f, 0.f};

  for (int kt = 0; kt < NT; ++kt) {
    __syncthreads();           // prior reads done; safe to overwrite LDS
    STAGE(kt);
    __syncthreads();           // drains vmcnt -> staged data visible
#pragma unroll
    for (int mf = 0; mf < 4; ++mf)
#pragma unroll
      for (int ks = 0; ks < 2; ++ks)
        aF[mf][ks] = *(const bf16x8*)(ldsp + aRd + ks * 8192 + mf * 256);
#pragma unroll
    for (int nf = 0; nf < 4; ++nf)
#pragma unroll
      for (int ks = 0; ks < 2; ++ks)
        bF[nf][ks] = *(const bf16x8*)(ldsp + bRd + ks * 8192 + nf * 256);
#pragma unroll
    for (int mf = 0; mf < 4; ++mf)
#pragma unroll
      for (int nf = 0; nf < 4; ++nf)
#pragma unroll
        for (int ks = 0; ks < 2; ++ks)
          acc[mf][nf] = __builtin_amdgcn_mfma_f32_16x16x32_bf16(
              bF[nf][ks], aF[mf][ks], acc[mf][nf], 0, 0, 0);
  }
  __syncthreads();  // LDS free for epilogue reuse

  // swapped operands => lane l15 = row(A), q*4+j = col(B)
  const int rowTile = tm << 7;
  const int colTile = tn << 7;

  if constexpr (MODE == 1) {
    // ---- epilogue -> PACKED H (bf16, gelu) ----
    unsigned short* Hb = (unsigned short*)Cout + (size_t)e * cStride;
    const float* bb = bias + (size_t)e * biasStride;
#pragma unroll
    for (int nf = 0; nf < 4; ++nf) {
      int col = colTile + wn * 64 + nf * 16 + q * 4;
      float4 bv = *(const float4*)(bb + col);
      // packed H coords for this frag column group
      size_t blk = ((size_t)(rowTile >> 8) * (N >> 6) + (col >> 6)) * 16384;
      int coff = ((rowTile >> 7) & 1) * 8192 + ((col & 63) >> 3) * 1024 +
                 (col & 7);
#pragma unroll
      for (int mf = 0; mf < 4; ++mf) {
        int r7 = wm * 64 + mf * 16 + l15;  // row & 127
        f32x4 v = acc[mf][nf];
        u16x4 o;
        o[0] = f2bf(gelu_f(v[0] + bv.x));
        o[1] = f2bf(gelu_f(v[1] + bv.y));
        o[2] = f2bf(gelu_f(v[2] + bv.z));
        o[3] = f2bf(gelu_f(v[3] + bv.w));
        *(u16x4*)(Hb + blk + coff + r7 * 8) = o;
      }
    }
  } else {
    // ---- epilogue -> row-major fp32 Y via LDS repack (coalesced 64B/thr) ----
    float* smf = (float*)ldsp;  // [32][132] fp32 = 16.9 KB
    float* Yb = (float*)Cout + (size_t)e * cStride;
    const float* bb = bias + (size_t)e * biasStride;
    const int srow = wm * 16 + l15;
    float4 bv[4];
#pragma unroll
    for (int nf = 0; nf < 4; ++nf)
      bv[nf] = *(const float4*)(bb + colTile + wn * 64 + nf * 16 + q * 4);
#pragma unroll
    for (int mf = 0; mf < 4; ++mf) {
#pragma unroll
      for (int nf = 0; nf < 4; ++nf) {
        f32x4 v = acc[mf][nf];
        f32x4 o = {v[0] + bv[nf].x, v[1] + bv[nf].y,
                   v[2] + bv[nf].z, v[3] + bv[nf].w};
        *(f32x4*)&smf[srow * 132 + wn * 64 + nf * 16 + q * 4] = o;
      }
      __syncthreads();
      {
        int r32 = tid >> 3, seg = tid & 7;  // 32 rows x 8 segs of 64B
        int row = rowTile + (r32 >> 4) * 64 + mf * 16 + (r32 & 15);
        float* yr = Yb + (size_t)row * N + colTile + seg * 16;
        float4 v0 = *(float4*)&smf[r32 * 132 + seg * 16 + 0];
        float4 v1 = *(float4*)&smf[r32 * 132 + seg * 16 + 4];
        float4 v2 = *(float4*)&smf[r32 * 132 + seg * 16 + 8];
        float4 v3 = *(float4*)&smf[r32 * 132 + seg * 16 + 12];
        *(float4*)(yr + 0) = v0;
        *(float4*)(yr + 4) = v1;
        *(float4*)(yr + 8) = v2;
        *(float4*)(yr + 12) = v3;
      }
      __syncthreads();
    }
  }
}

extern "C" void kernel_launch(void* const* d_in, const int* in_sizes, int n_in,
                              void* d_out, int out_size, void* d_ws, size_t ws_size,
                              hipStream_t stream) {
  const float* X = (const float*)d_in[0];   // [1][E*C][D]
  const float* W1 = (const float*)d_in[1];  // [E][D][F]
  const float* b1 = (const float*)d_in[2];  // [E][F]
  const float* W2 = (const float*)d_in[3];  // [E][F][D]
  const float* b2 = (const float*)d_in[4];  // [E][D]
  float* Y = (float*)d_out;                 // [1][E*C][D]

  const size_t szX = (size_t)C_ * D_ * 2;
  const size_t szW1 = (size_t)F_ * D_ * 2;
  const size_t szW2 = (size_t)D_ * F_ * 2;
  const size_t szH = (size_t)C_ * F_ * 2;
  const size_t fixed = szX + szW1 + szW2;

  int g = 0;
  {
    const int cands[4] = {8, 4, 2, 1};
    for (int i = 0; i < 4; ++i)
      if ((fixed + szH) * (size_t)cands[i] <= ws_size) { g = cands[i]; break; }
  }
  int RC = C_;
  if (g == 0) {  // tiny-ws fallback: chunk rows (256-granular, packed panels)
    g = 1;
    size_t avail = ws_size > fixed ? ws_size - fixed : 0;
    RC = (int)(avail / ((size_t)F_ * 2));
    RC = (RC / 256) * 256;
    if (RC < 256) RC = 256;
    if (RC > C_) RC = C_;
  }

  unsigned short* XP = (unsigned short*)d_ws;              // [g] packed X
  unsigned short* W1P = XP + (size_t)g * C_ * D_;          // [g] packed W1^T
  unsigned short* W2P = W1P + (size_t)g * F_ * D_;         // [g] packed W2^T
  unsigned short* HP = W2P + (size_t)g * D_ * F_;          // [g] packed H

  const int numN1 = F_ / 128;  // 32
  const int numN2 = D_ / 128;  // 8
  const int NT1 = D_ / 64;     // 16

  for (int e0 = 0; e0 < E_; e0 += g) {
    pack_rm_kernel<<<dim3(C_ / 256, D_ / 64, g), 256, 0, stream>>>(
        X + (size_t)e0 * C_ * D_, XP, C_, D_);
    pack_tr_kernel<<<dim3(F_ / 256, D_ / 64, g), 256, 0, stream>>>(
        W1 + (size_t)e0 * D_ * F_, W1P, D_, F_);
    pack_tr_kernel<<<dim3(D_ / 256, F_ / 64, g), 256, 0, stream>>>(
        W2 + (size_t)e0 * F_ * D_, W2P, F_, D_);

    for (int r0 = 0; r0 < C_; r0 += RC) {
      int numM = RC / 128;
      // GEMM1: H = gelu(X @ W1 + b1) -> packed H, [RC x F], K = D
      gemm128_kernel<1><<<dim3((unsigned)(numM * numN1 * g)), 256, 0, stream>>>(
          XP + (size_t)(r0 >> 8) * NT1 * 16384, W1P, b1 + (size_t)e0 * F_,
          (void*)HP, D_, F_, numM, numN1,
          (size_t)C_ * D_, (size_t)F_ * D_, (size_t)RC * F_, F_);
      // GEMM2: Y = H @ W2 + b2, [RC x D], K = F
      gemm128_kernel<0><<<dim3((unsigned)(numM * numN2 * g)), 256, 0, stream>>>(
          HP, W2P, b2 + (size_t)e0 * D_,
          (void*)(Y + (size_t)e0 * C_ * D_ + (size_t)r0 * D_),
          F_, D_, numM, numN2,
          (size_t)RC * F_, (size_t)D_ * F_, (size_t)C_ * D_, D_);
    }
  }
}

// Round 11
// 725.081 us; speedup vs baseline: 7.0951x; 1.4773x over previous
//
#include <hip/hip_runtime.h>
#include <stdint.h>

// Experts FFN: E experts, C tokens/expert, D model, F ff
#define E_ 8
#define C_ 4096
#define D_ 1024
#define F_ 4096

typedef __attribute__((ext_vector_type(8))) short bf16x8;
typedef __attribute__((ext_vector_type(4))) float f32x4;
typedef __attribute__((ext_vector_type(8))) unsigned short u16x8;
typedef __attribute__((ext_vector_type(4))) unsigned short u16x4;

__device__ __forceinline__ unsigned short f2bf(float x) {
  union { float f; uint32_t u; } v; v.f = x;
  uint32_t r = v.u + 0x7FFFu + ((v.u >> 16) & 1u);  // RNE
  return (unsigned short)(r >> 16);
}

// JAX gelu (approximate=True)
__device__ __forceinline__ float gelu_f(float x) {
  float x3 = x * x * x;
  float u = 0.7978845608028654f * __builtin_fmaf(0.044715f, x3, x);
  float t = __expf(2.0f * u);
  float th = 1.0f - 2.0f / (t + 1.0f);
  return 0.5f * x * (1.0f + th);
}

// ---------------- elementwise fp32 -> bf16 ----------------
__global__ void convert_bf16_kernel(const float* __restrict__ in,
                                    unsigned short* __restrict__ out, size_t n) {
  size_t i = ((size_t)blockIdx.x * blockDim.x + threadIdx.x) * 8;
  size_t stride = (size_t)gridDim.x * blockDim.x * 8;
  for (; i < n; i += stride) {
    float4 a = *(const float4*)(in + i);
    float4 b = *(const float4*)(in + i + 4);
    u16x8 o;
    o[0] = f2bf(a.x); o[1] = f2bf(a.y); o[2] = f2bf(a.z); o[3] = f2bf(a.w);
    o[4] = f2bf(b.x); o[5] = f2bf(b.y); o[6] = f2bf(b.z); o[7] = f2bf(b.w);
    *(u16x8*)(out + i) = o;
  }
}

// ---------------- tiled transpose: fp32 [K][N] -> bf16 [N][K] ----------------
__global__ void transpose_bf16_kernel(const float* __restrict__ in,
                                      unsigned short* __restrict__ out,
                                      int K, int N) {
  const int ge = blockIdx.z;
  const float* src = in + (size_t)ge * K * N;
  unsigned short* dst = out + (size_t)ge * K * N;
  __shared__ float tile[32][33];
  int t = threadIdx.x;
  int tx = t & 31, ty = t >> 5;  // 32 x 8
  int k0 = blockIdx.x * 32, n0 = blockIdx.y * 32;
#pragma unroll
  for (int p = 0; p < 4; ++p)
    tile[ty + p * 8][tx] = src[(size_t)(k0 + ty + p * 8) * N + n0 + tx];
  __syncthreads();
#pragma unroll
  for (int p = 0; p < 4; ++p)
    dst[(size_t)(n0 + ty + p * 8) * K + k0 + tx] = f2bf(tile[tx][ty + p * 8]);
}

// ---------------- async global->LDS ----------------
typedef const __attribute__((address_space(1))) uint32_t* gas1_ptr;
typedef __attribute__((address_space(3))) uint32_t* las3_ptr;

__device__ __forceinline__ void async16(const void* g, void* l) {
  __builtin_amdgcn_global_load_lds((gas1_ptr)(uintptr_t)g, (las3_ptr)(uintptr_t)l,
                                   16, 0, 0);
}

// ============================================================================
// 256x256 8-phase bf16 GEMM (m201 structure, plain HIP):
//   C[M][N] = A[M][K] * B[N][K]^T (+bias) ; MODE 0: fp32 out; MODE 1: bf16 gelu
// 512 thr = 8 waves (2M x 4N), per-wave 128x64, BK=64, LDS 128 KiB 2-dbuf.
// Phase quadrant order per K-tile: (0,0),(0,1),(1,1),(1,0); B-frags of nh=0
// kept in regs from ph1 to ph4; staging targets region freed one phase earlier.
// vmcnt(6) only at ph4/ph8 => 3 half-tiles (6 loads) in flight.
// Swapped MFMA operands (mfma(b,a)): lane l15 -> M row, (q*4+j) -> N col,
// so epilogue stores are float4 / ushort4 packed.
// [Session best: 725 us total, verified passing — resubmitted after R10's
// experimental GEMM2 loop failed correctness.]
// ============================================================================

#define SYNC_PRE() do { \
    __builtin_amdgcn_sched_barrier(0); \
    __builtin_amdgcn_s_barrier(); \
    asm volatile("s_waitcnt lgkmcnt(0)" ::: "memory"); \
    __builtin_amdgcn_sched_barrier(0); \
    __builtin_amdgcn_s_setprio(1); \
  } while (0)

#define SYNC_POST() do { \
    __builtin_amdgcn_s_setprio(0); \
    __builtin_amdgcn_sched_barrier(0); \
    __builtin_amdgcn_s_barrier(); \
    __builtin_amdgcn_sched_barrier(0); \
  } while (0)

#define SYNC_POST_VM() do { \
    __builtin_amdgcn_s_setprio(0); \
    __builtin_amdgcn_sched_barrier(0); \
    asm volatile("s_waitcnt vmcnt(6)" ::: "memory"); \
    __builtin_amdgcn_s_barrier(); \
    __builtin_amdgcn_sched_barrier(0); \
  } while (0)

template <int MODE>
__global__ __launch_bounds__(512, 2) void gemm256_kernel(
    const unsigned short* __restrict__ A,  // [M][K] bf16
    const unsigned short* __restrict__ B,  // [N][K] bf16
    const float* __restrict__ bias,        // [N]
    void* __restrict__ Cout,
    int K, int N, int numM, int numN,
    size_t aStride, size_t bStride, size_t cStride, int biasStride) {
  __shared__ char lds[131072];
  char* ldsp = (char*)lds;

  const int NT = K >> 6;      // 64-wide K tiles
  const int NITER = NT >> 1;

  // bijective XCD swizzle (m204)
  int lin = blockIdx.x;
  int nwg = gridDim.x;
  int qq = nwg >> 3, rr8 = nwg & 7;
  int xcd = lin & 7, idx = lin >> 3;
  int wg = (xcd < rr8 ? xcd * (qq + 1) : rr8 * (qq + 1) + (xcd - rr8) * qq) + idx;
  int per = numM * numN;
  int e = wg / per;
  int rem = wg - e * per;
  int tm = rem % numM, tn = rem / numM;

  A += (size_t)e * aStride;
  B += (size_t)e * bStride;
  bias += (size_t)e * biasStride;

  const int rowTile = tm << 8;
  const int colTile = tn << 8;

  const int tid = threadIdx.x;
  const int lane = tid & 63;
  const int w = tid >> 6;
  const int wm = w & 1, wn = w >> 1;
  const int l15 = lane & 15, q = lane >> 4;

  const size_t ldB = (size_t)K * 2;  // row bytes for A and B

  // ---- staging precompute (per-thread, loop-invariant) ----
  const int rlo = tid >> 3, kc = tid & 7;
  const int swzsrc = ((kc ^ (rlo & 7)) << 4);      // pre-swizzled global chunk
  const char* aS0 = (const char*)A + (size_t)(rowTile + rlo) * ldB + swzsrc;
  const char* aS1 = (const char*)A + (size_t)(rowTile + rlo + 128) * ldB + swzsrc;
  const int bcol = (rlo & 31) + ((rlo >> 5) << 6);
  const char* bS0 = (const char*)B + (size_t)(colTile + bcol) * ldB + swzsrc;
  const char* bS1 = (const char*)B + (size_t)(colTile + bcol + 128) * ldB + swzsrc;
  const size_t a64 = (size_t)64 * ldB;   // A-half stride (rows +64)
  const size_t b32 = (size_t)32 * ldB;   // B-half stride (cols +32)
  const int aD0 = rlo * 128 + kc * 16;
  const int aD1 = aD0 + 16384;
  const int bD0 = 32768 + bcol * 128 + kc * 16;
  const int bD1 = bD0 + 16384;

#define STAGE_A(bb, Ah, kt) do { \
    size_t kb = (size_t)(kt) * 128; \
    int dbase = (bb) * 65536 + (Ah) * 8192; \
    async16(aS0 + (Ah) * a64 + kb, ldsp + dbase + aD0); \
    async16(aS1 + (Ah) * a64 + kb, ldsp + dbase + aD1); \
  } while (0)

#define STAGE_B(bb, Bh, kt) do { \
    size_t kb = (size_t)(kt) * 128; \
    int dbase = (bb) * 65536 + (Bh) * 4096; \
    async16(bS0 + (Bh) * b32 + kb, ldsp + dbase + bD0); \
    async16(bS1 + (Bh) * b32 + kb, ldsp + dbase + bD1); \
  } while (0)

  // ---- LDS read bases (k-offset = (q*16 ^ swz) XOR ks*64) ----
  const int k0 = (q * 16) ^ ((l15 & 7) << 4);
  const int aRdBase = wm * 16384 + l15 * 128;           // + b*65536 + mf*2048
  const int bRdBase = 32768 + wn * 8192 + l15 * 128;    // + b*65536 + nf*2048

  bf16x8 aR[4][2], bR0[2][2], bR1[2][2];
  f32x4 acc[8][4];
#pragma unroll
  for (int m = 0; m < 8; ++m)
#pragma unroll
    for (int n = 0; n < 4; ++n) acc[m][n] = {0.f, 0.f, 0.f, 0.f};

#define READ_A(bb, mh) do { \
    _Pragma("unroll") for (int m4 = 0; m4 < 4; ++m4) \
    _Pragma("unroll") for (int ks = 0; ks < 2; ++ks) \
      aR[m4][ks] = *(const bf16x8*)(ldsp + (bb) * 65536 + aRdBase + \
                                    ((mh) * 4 + m4) * 2048 + (k0 ^ (ks << 6))); \
  } while (0)

#define READ_B(dst, bb, nh) do { \
    _Pragma("unroll") for (int n2 = 0; n2 < 2; ++n2) \
    _Pragma("unroll") for (int ks = 0; ks < 2; ++ks) \
      dst[n2][ks] = *(const bf16x8*)(ldsp + (bb) * 65536 + bRdBase + \
                                     ((nh) * 2 + n2) * 2048 + (k0 ^ (ks << 6))); \
  } while (0)

#define MFMA_QUAD(mh, nh, BR) do { \
    _Pragma("unroll") for (int m4 = 0; m4 < 4; ++m4) \
    _Pragma("unroll") for (int n2 = 0; n2 < 2; ++n2) \
    _Pragma("unroll") for (int ks = 0; ks < 2; ++ks) \
      acc[(mh) * 4 + m4][(nh) * 2 + n2] = \
          __builtin_amdgcn_mfma_f32_16x16x32_bf16( \
              BR[n2][ks], aR[m4][ks], acc[(mh) * 4 + m4][(nh) * 2 + n2], 0, 0, 0); \
  } while (0)

  // ---- prologue: tile0 -> buf0 (all 4 halves), tile1 -> buf1 (A0,B0,A1) ----
  STAGE_A(0, 0, 0); STAGE_B(0, 0, 0); STAGE_A(0, 1, 0); STAGE_B(0, 1, 0);
  STAGE_A(1, 0, 1); STAGE_B(1, 0, 1); STAGE_A(1, 1, 1);
  asm volatile("s_waitcnt vmcnt(6)" ::: "memory");  // tile0 landed
  __builtin_amdgcn_sched_barrier(0);
  __builtin_amdgcn_s_barrier();
  __builtin_amdgcn_sched_barrier(0);

  for (int j = 0; j < NITER; ++j) {
    int t1 = 2 * j + 1;
    int t2 = 2 * j + 2; if (t2 > NT - 1) t2 = NT - 1;  // clamped dummy stages
    int t3 = 2 * j + 3; if (t3 > NT - 1) t3 = NT - 1;  // land in freed regions

    // ph1: buf0 quad(0,0); stage buf1.B1 <- t1
    READ_A(0, 0); READ_B(bR0, 0, 0);
    STAGE_B(1, 1, t1);
    SYNC_PRE(); MFMA_QUAD(0, 0, bR0); SYNC_POST();
    // ph2: buf0 quad(0,1); stage buf0.A0 <- t2  (A0 freed after ph1)
    READ_B(bR1, 0, 1);
    STAGE_A(0, 0, t2);
    SYNC_PRE(); MFMA_QUAD(0, 1, bR1); SYNC_POST();
    // ph3: buf0 quad(1,1); stage buf0.B0 <- t2  (B0 LDS-freed after ph1)
    READ_A(0, 1);
    STAGE_B(0, 0, t2);
    SYNC_PRE(); MFMA_QUAD(1, 1, bR1); SYNC_POST();
    // ph4: buf0 quad(1,0) (regs only); stage buf0.A1 <- t2; vmcnt(6)
    STAGE_A(0, 1, t2);
    SYNC_PRE(); MFMA_QUAD(1, 0, bR0); SYNC_POST_VM();
    // ph5: buf1 quad(0,0); stage buf0.B1 <- t2  (B1 freed after ph2)
    READ_A(1, 0); READ_B(bR0, 1, 0);
    STAGE_B(0, 1, t2);
    SYNC_PRE(); MFMA_QUAD(0, 0, bR0); SYNC_POST();
    // ph6: buf1 quad(0,1); stage buf1.A0 <- t3
    READ_B(bR1, 1, 1);
    STAGE_A(1, 0, t3);
    SYNC_PRE(); MFMA_QUAD(0, 1, bR1); SYNC_POST();
    // ph7: buf1 quad(1,1); stage buf1.B0 <- t3
    READ_A(1, 1);
    STAGE_B(1, 0, t3);
    SYNC_PRE(); MFMA_QUAD(1, 1, bR1); SYNC_POST();
    // ph8: buf1 quad(1,0); stage buf1.A1 <- t3; vmcnt(6)
    STAGE_A(1, 1, t3);
    SYNC_PRE(); MFMA_QUAD(1, 0, bR0); SYNC_POST_VM();
  }
  asm volatile("s_waitcnt vmcnt(0)" ::: "memory");  // drain dummy stages

  // ---- epilogue: swapped layout => lane l15 = row, q*4+j = col ----
#pragma unroll
  for (int mf = 0; mf < 8; ++mf) {
    int row = rowTile + wm * 128 + mf * 16 + l15;
#pragma unroll
    for (int nf = 0; nf < 4; ++nf) {
      int col = colTile + wn * 64 + nf * 16 + q * 4;
      float4 bv = *(const float4*)(bias + col);
      f32x4 v = acc[mf][nf];
      if constexpr (MODE == 1) {
        u16x4 o;
        o[0] = f2bf(gelu_f(v[0] + bv.x));
        o[1] = f2bf(gelu_f(v[1] + bv.y));
        o[2] = f2bf(gelu_f(v[2] + bv.z));
        o[3] = f2bf(gelu_f(v[3] + bv.w));
        *(u16x4*)((unsigned short*)Cout + (size_t)e * cStride +
                  (size_t)row * N + col) = o;
      } else {
        float4 o;
        o.x = v[0] + bv.x; o.y = v[1] + bv.y;
        o.z = v[2] + bv.z; o.w = v[3] + bv.w;
        *(float4*)((float*)Cout + (size_t)e * cStride + (size_t)row * N + col) = o;
      }
    }
  }
}

extern "C" void kernel_launch(void* const* d_in, const int* in_sizes, int n_in,
                              void* d_out, int out_size, void* d_ws, size_t ws_size,
                              hipStream_t stream) {
  const float* X = (const float*)d_in[0];   // [1][E*C][D]
  const float* W1 = (const float*)d_in[1];  // [E][D][F]
  const float* b1 = (const float*)d_in[2];  // [E][F]
  const float* W2 = (const float*)d_in[3];  // [E][F][D]
  const float* b2 = (const float*)d_in[4];  // [E][D]
  float* Y = (float*)d_out;                 // [1][E*C][D]

  const size_t szX = (size_t)C_ * D_ * 2;
  const size_t szW1 = (size_t)F_ * D_ * 2;
  const size_t szW2 = (size_t)D_ * F_ * 2;
  const size_t szH = (size_t)C_ * F_ * 2;
  const size_t fixed = szX + szW1 + szW2;

  int g = 0;
  {
    const int cands[4] = {8, 4, 2, 1};
    for (int i = 0; i < 4; ++i)
      if ((fixed + szH) * (size_t)cands[i] <= ws_size) { g = cands[i]; break; }
  }
  int RC = C_;
  if (g == 0) {  // tiny-ws fallback: chunk rows (256-granular for BM=256)
    g = 1;
    size_t avail = ws_size > fixed ? ws_size - fixed : 0;
    RC = (int)(avail / ((size_t)F_ * 2));
    RC = (RC / 256) * 256;
    if (RC < 256) RC = 256;
    if (RC > C_) RC = C_;
  }

  unsigned short* XB = (unsigned short*)d_ws;              // [g][C][D]
  unsigned short* W1T = XB + (size_t)g * C_ * D_;          // [g][F][D]
  unsigned short* W2T = W1T + (size_t)g * F_ * D_;         // [g][D][F]
  unsigned short* H = W2T + (size_t)g * D_ * F_;           // [g][RC][F]

  const int numN1 = F_ / 256;  // 16
  const int numN2 = D_ / 256;  // 4

  for (int e0 = 0; e0 < E_; e0 += g) {
    {
      size_t n = (size_t)g * C_ * D_;
      size_t nb = (n / 8 + 255) / 256;
      if (nb > 2048) nb = 2048;
      convert_bf16_kernel<<<dim3((unsigned)nb), 256, 0, stream>>>(
          X + (size_t)e0 * C_ * D_, XB, n);
    }
    transpose_bf16_kernel<<<dim3(D_ / 32, F_ / 32, g), 256, 0, stream>>>(
        W1 + (size_t)e0 * D_ * F_, W1T, D_, F_);
    transpose_bf16_kernel<<<dim3(F_ / 32, D_ / 32, g), 256, 0, stream>>>(
        W2 + (size_t)e0 * F_ * D_, W2T, F_, D_);

    for (int r0 = 0; r0 < C_; r0 += RC) {
      int numM = RC / 256;
      // GEMM1: H = gelu(XB @ W1T^T + b1), [RC x F], K = D
      gemm256_kernel<1><<<dim3((unsigned)(numM * numN1 * g)), 512, 0, stream>>>(
          XB + (size_t)r0 * D_, W1T, b1 + (size_t)e0 * F_, (void*)H,
          D_, F_, numM, numN1,
          (size_t)C_ * D_, (size_t)F_ * D_, (size_t)RC * F_, F_);
      // GEMM2: Y = H @ W2T^T + b2, [RC x D], K = F
      gemm256_kernel<0><<<dim3((unsigned)(numM * numN2 * g)), 512, 0, stream>>>(
          H, W2T, b2 + (size_t)e0 * D_,
          (void*)(Y + (size_t)e0 * C_ * D_ + (size_t)r0 * D_),
          F_, D_, numM, numN2,
          (size_t)RC * F_, (size_t)D_ * F_, (size_t)C_ * D_, D_);
    }
  }
}